// Round 1
// baseline (452.034 us; speedup 1.0000x reference)
//
#include <hip/hip_runtime.h>
#include <math.h>

// NSA attention (round 13: sel_topk rebuilt as one-shot sorted-merge top-16.
// Round 12 counters: sel_topk = 4x68 us = 70% of runtime, VALUBusy 52%,
// HBM 13%, occupancy 36% -> latency-bound on 16 rounds x 6-hop shfl-max
// chains (96 dependent cross-lane hops) + divergent refresh. New design:
// the output only needs the top-16 SET (softmax is order-invariant, u64
// packing keeps jax tie-break exact), so: per-lane static bitonic build of
// sorted-16-of-32 (pure VALU, zero cross-lane), then ONE 6-hop butterfly
// merging sorted-16 lists. No refresh, no divergence, throughput-bound.
// B=2 L=2048 C=256 H=8 HD=32 BS=16 SK=16 window=+-32.

#define Bc 2
#define Lc 2048
#define Cc 256
#define Hc 8
#define HDc 32
#define BHc 16          // B*H
#define NBc 128         // L/BS
#define ROWSc 4096      // B*L
#define TROWSc 32768    // B*H*L
#define SCALEc 0.17677669529663687f

typedef unsigned long long u64;

// ---------- helpers ----------

__device__ __forceinline__ float dot32q(const float* qr, const float* kr) {
  const float4* k4 = (const float4*)kr;
  float p0 = 0.f, p1 = 0.f, p2 = 0.f, p3 = 0.f;
#pragma unroll
  for (int j = 0; j < 8; j += 4) {
    float4 a = k4[j], b = k4[j + 1], c = k4[j + 2], e = k4[j + 3];
    p0 += a.x * qr[4 * j + 0] + a.y * qr[4 * j + 1] + a.z * qr[4 * j + 2] + a.w * qr[4 * j + 3];
    p1 += b.x * qr[4 * j + 4] + b.y * qr[4 * j + 5] + b.z * qr[4 * j + 6] + b.w * qr[4 * j + 7];
    p2 += c.x * qr[4 * j + 8] + c.y * qr[4 * j + 9] + c.z * qr[4 * j + 10] + c.w * qr[4 * j + 11];
    p3 += e.x * qr[4 * j + 12] + e.y * qr[4 * j + 13] + e.z * qr[4 * j + 14] + e.w * qr[4 * j + 15];
  }
  return (p0 + p1) + (p2 + p3);
}

// order-preserving float<->int maps
__device__ __forceinline__ int f2o(float x) {
  const int i = __float_as_int(x);
  return i >= 0 ? i : (i ^ 0x7fffffff);
}
__device__ __forceinline__ float o2f(int i) {
  return __int_as_float(i >= 0 ? i : (i ^ 0x7fffffff));
}

// compare-exchange: a = max, b = min (descending order)
__device__ __forceinline__ void ce(u64& a, u64& b) {
  const bool c = a > b;
  const u64 mx = c ? a : b;
  const u64 mn = c ? b : a;
  a = mx;
  b = mn;
}

// bitonic merge network, descending result. Input must be bitonic
// (e.g. desc-run ++ reversed desc-run = valley). Fully static after unroll.
template <int N>
__device__ __forceinline__ void bmerge(u64* x) {
#pragma unroll
  for (int k = N / 2; k >= 1; k /= 2) {
#pragma unroll
    for (int i = 0; i < N; ++i) {
      if ((i & k) == 0) ce(x[i], x[i + k]);
    }
  }
}

// merge adjacent descending runs of length HALF into runs of 2*HALF (in place
// over 32 elements)
template <int HALF>
__device__ __forceinline__ void merge_runs(u64* m) {
#pragma unroll
  for (int g = 0; g < 32; g += 2 * HALF) {
    u64 x[2 * HALF];
#pragma unroll
    for (int i = 0; i < HALF; ++i) x[i] = m[g + i];
#pragma unroll
    for (int i = 0; i < HALF; ++i) x[HALF + i] = m[g + 2 * HALF - 1 - i];
    bmerge<2 * HALF>(x);
#pragma unroll
    for (int i = 0; i < 2 * HALF; ++i) m[g + i] = x[i];
  }
}

__device__ __forceinline__ u64 shflx64(u64 v, int mask) {
  const int lo = __shfl_xor((int)(unsigned)(v & 0xffffffffull), mask);
  const int hi = __shfl_xor((int)(unsigned)(v >> 32), mask);
  return ((u64)(unsigned)hi << 32) | (u64)(unsigned)lo;
}

// ---------- projections ----------
// X(4096,256) @ W(256,256) + bias. headlayout=1: store [b*H+h][l][d]; else [row][c].
__global__ __launch_bounds__(256) void proj_kernel(const float* __restrict__ X,
                                                   const float* __restrict__ W,
                                                   const float* __restrict__ bias,
                                                   float* __restrict__ outp, int headlayout) {
  __shared__ float xs[8 * Cc];
  const int tid = threadIdx.x;
  const int row0 = blockIdx.x * 8;
  {
    const float4* xin = (const float4*)(X + (size_t)row0 * Cc);
    float4* xsv = (float4*)xs;
    xsv[tid] = xin[tid];
    xsv[tid + 256] = xin[tid + 256];
  }
  __syncthreads();
  const int c0 = (tid & 63) * 4;  // 4 consecutive cols
  const int rh = tid >> 6;        // wave id; 2 rows per wave
  float acc[2][4];
#pragma unroll
  for (int r = 0; r < 2; ++r)
#pragma unroll
    for (int c = 0; c < 4; ++c) acc[r][c] = 0.f;

#pragma unroll 4
  for (int d4 = 0; d4 < 64; ++d4) {
    const int d = d4 * 4;
    const float4 w0 = *(const float4*)(W + (size_t)(d + 0) * Cc + c0);
    const float4 w1 = *(const float4*)(W + (size_t)(d + 1) * Cc + c0);
    const float4 w2 = *(const float4*)(W + (size_t)(d + 2) * Cc + c0);
    const float4 w3 = *(const float4*)(W + (size_t)(d + 3) * Cc + c0);
#pragma unroll
    for (int r = 0; r < 2; ++r) {
      const float4 xv = *(const float4*)(xs + (rh * 2 + r) * Cc + d);
      acc[r][0] += xv.x * w0.x + xv.y * w1.x + xv.z * w2.x + xv.w * w3.x;
      acc[r][1] += xv.x * w0.y + xv.y * w1.y + xv.z * w2.y + xv.w * w3.y;
      acc[r][2] += xv.x * w0.z + xv.y * w1.z + xv.z * w2.z + xv.w * w3.z;
      acc[r][3] += xv.x * w0.w + xv.y * w1.w + xv.z * w2.w + xv.w * w3.w;
    }
  }
  const float4 bv = *(const float4*)(bias + c0);
#pragma unroll
  for (int r = 0; r < 2; ++r) {
    const int grow = row0 + rh * 2 + r;
    const float4 o = make_float4(acc[r][0] + bv.x, acc[r][1] + bv.y,
                                 acc[r][2] + bv.z, acc[r][3] + bv.w);
    if (headlayout) {
      const int b = grow >> 11, l = grow & 2047;
      const int h = c0 >> 5, dd = c0 & 31;
      *(float4*)(outp + (((size_t)(b * Hc + h) * Lc + l) * HDc + dd)) = o;
    } else {
      *(float4*)(outp + (size_t)grow * Cc + c0) = o;
    }
  }
}

// gate = sigmoid(query @ Wg + bg), one thread per row
__global__ __launch_bounds__(256) void gate_kernel(const float* __restrict__ query,
                                                   const float* __restrict__ Wg,
                                                   const float* __restrict__ bg,
                                                   float* __restrict__ gatep) {
  const int row = blockIdx.x * 256 + threadIdx.x;
  const float4* x4 = (const float4*)(query + (size_t)row * Cc);
  float a0 = bg[0], a1 = bg[1], a2 = bg[2];
#pragma unroll 8
  for (int d4 = 0; d4 < 64; ++d4) {
    const float4 xv = x4[d4];
    const float* wr = Wg + d4 * 12;
    a0 += xv.x * wr[0] + xv.y * wr[3] + xv.z * wr[6] + xv.w * wr[9];
    a1 += xv.x * wr[1] + xv.y * wr[4] + xv.z * wr[7] + xv.w * wr[10];
    a2 += xv.x * wr[2] + xv.y * wr[5] + xv.z * wr[8] + xv.w * wr[11];
  }
  float* g = gatep + (size_t)row * 3;
  g[0] = 1.f / (1.f + __expf(-a0));
  g[1] = 1.f / (1.f + __expf(-a1));
  g[2] = 1.f / (1.f + __expf(-a2));
}

// ---------- compressed K/V ----------
__global__ __launch_bounds__(256) void cmpkv_kernel(const float* __restrict__ kh,
                                                    const float* __restrict__ vh,
                                                    const float* __restrict__ WKc,
                                                    const float* __restrict__ WVc,
                                                    const float* __restrict__ Wpe,
                                                    float* __restrict__ Kcp,
                                                    float* __restrict__ Vcp) {
  const int idx = blockIdx.x * 256 + threadIdx.x;  // 65536 = bh*128*32
  const int d = idx & 31, n = (idx >> 5) & 127, bh = idx >> 12;
  float pk = 0.f, pv = 0.f;
#pragma unroll
  for (int s = 0; s < 16; ++s) {
    const float pe = Wpe[s * Cc + d];
    pk += pe * WKc[s];
    pv += pe * WVc[s];
  }
  const float* kp = kh + ((size_t)bh * Lc + n * 16) * HDc + d;
  const float* vp = vh + ((size_t)bh * Lc + n * 16) * HDc + d;
  float ak = pk, av = pv;
#pragma unroll
  for (int s = 0; s < 16; ++s) {
    ak += kp[s * HDc] * WKc[s];
    av += vp[s * HDc] * WVc[s];
  }
  Kcp[idx] = ak;
  Vcp[idx] = av;
}

// ---------- compressed attention ----------
// Block = 512 thr / 64 rows of one head. Phase A: lane=row, wave w owns keys
// [w*16, w*16+16) via wave-uniform s_load (zero TA); scores -> LDS sc[key][row]
// + per-wave row-max partials. Phase B: thread=(row, 4-dim group); per key one
// broadcast LDS read + one 128B-line float4 V load; fused exp/z/PV; coalesced
// float4 store.
__global__ __launch_bounds__(512) void cmp_attn_kernel(const float* __restrict__ qh,
                                                       const float* __restrict__ Kcp,
                                                       const float* __restrict__ Vcp,
                                                       float* __restrict__ ocmp) {
  __shared__ float sc[128][65];
  __shared__ float pm[8][64];
  const int tid = threadIdx.x, lane = tid & 63;
  const int w = __builtin_amdgcn_readfirstlane(tid >> 6);
  const int bh = blockIdx.y;
  const int lrow = blockIdx.x * 64 + lane;
  const float* q = qh + ((size_t)bh * Lc + lrow) * HDc;
  float qr[HDc];
#pragma unroll
  for (int d = 0; d < HDc; ++d) qr[d] = q[d] * SCALEc;
  const float* kcb = Kcp + (size_t)bh * NBc * HDc;
  float pmax = -1e30f;
#pragma unroll
  for (int i = 0; i < 16; ++i) {
    const int key = w * 16 + i;  // uniform
    const float s = dot32q(qr, kcb + (size_t)key * HDc);
    sc[key][lane] = s;
    pmax = fmaxf(pmax, s);
  }
  pm[w][lane] = pmax;
  __syncthreads();

  const int row = tid >> 3;        // 0..63
  const int dg = (tid & 7) * 4;    // dim-group base
  float m = pm[0][row];
#pragma unroll
  for (int i = 1; i < 8; ++i) m = fmaxf(m, pm[i][row]);
  const float* vcb = Vcp + (size_t)bh * NBc * HDc + dg;
  float o0 = 0.f, o1 = 0.f, o2 = 0.f, o3 = 0.f, z = 0.f;
#pragma unroll 4
  for (int key = 0; key < 128; ++key) {
    const float wgt = __expf(sc[key][row] - m);
    z += wgt;
    const float4 v = *(const float4*)(vcb + key * HDc);
    o0 += wgt * v.x; o1 += wgt * v.y; o2 += wgt * v.z; o3 += wgt * v.w;
  }
  const float iz = 1.f / z;
  *(float4*)(ocmp + ((size_t)bh * Lc + blockIdx.x * 64 + row) * HDc + dg) =
      make_float4(o0 * iz, o1 * iz, o2 * iz, o3 * iz);
}

// ---------- selection score pass ----------
// Block = 512 thr = 8 waves, 64 rows (lane = row) x 512 keys (key-quarter
// blockIdx.y). Wave w computes keys [q0 + strip*64 + w*8, +8) per strip.
// w is readfirstlane'd -> K addresses are provably wave-uniform -> s_load
// (SMEM/K$) for K rows, v_fmac v,s,v for the dot: zero TA traffic for K.
// LDS transpose -> coalesced scores[row][key] stores. Grid (32,4,G).
__global__ __launch_bounds__(512) void score_kernel(const float* __restrict__ qh,
                                                    const float* __restrict__ kh,
                                                    float* __restrict__ scores, int bh0) {
  __shared__ float sc[64][65];  // [key-in-strip][row], pad 65 -> conflict-free both phases
  const int tid = threadIdx.x, lane = tid & 63;
  const int w = __builtin_amdgcn_readfirstlane(tid >> 6);  // wave id as SGPR (uniform)
  const int hloc = blockIdx.z;           // head within chunk
  const int bh = bh0 + hloc;
  const int q0 = blockIdx.y * 512;       // key-quarter base
  const int lrow = blockIdx.x * 64 + lane;  // row within head
  const float* q = qh + ((size_t)bh * Lc + lrow) * HDc;
  float qr[HDc];
#pragma unroll
  for (int d = 0; d < HDc; ++d) qr[d] = q[d] * SCALEc;
  const float* kb = kh + (size_t)bh * Lc * HDc;
  // store-phase thread mapping: 8 consecutive threads cover one row's 64 keys
  const int srow = tid >> 3;        // 0..63 row-in-tile
  const int skg = (tid & 7) * 8;    // key-group base within strip
  float* srowp = scores + ((size_t)hloc * Lc + (size_t)blockIdx.x * 64 + srow) * Lc + q0;

  for (int strip = 0; strip < 8; ++strip) {
    const int k0 = q0 + strip * 64 + w * 8;  // uniform (SGPR) expression
    float s[8];
#pragma unroll
    for (int j = 0; j < 8; ++j) s[j] = dot32q(qr, kb + (size_t)(k0 + j) * HDc);
    __syncthreads();  // previous strip's store-phase reads complete
#pragma unroll
    for (int j = 0; j < 8; ++j) sc[w * 8 + j][lane] = s[j];
    __syncthreads();
    // store: read sc[skg..skg+7][srow], write 32 B contiguous
    float v[8];
#pragma unroll
    for (int j = 0; j < 8; ++j) v[j] = sc[skg + j][srow];
    float4* dst = (float4*)(srowp + strip * 64 + skg);
    dst[0] = make_float4(v[0], v[1], v[2], v[3]);
    dst[1] = make_float4(v[4], v[5], v[6], v[7]);
  }
}

// ---------- selection top-16 + softmax + V (one-shot sorted merge) ----------
// One wave per row. Lane l owns keys {(i/4)*256 + 4l + i%4} (coalesced float4
// loads). Each score packed into a globally-unique u64 ordinal:
//   ((f2o(s)^0x80000000) << 11) | (2047 - key)
// -> integer order = (score desc, key asc) EXACTLY (bit-exact top_k ties).
// The softmax+PV output is order-invariant in the selected SET, so top-16
// extraction is done in one shot: per-lane bitonic build of its sorted
// top-16-of-32 (static CE network, zero cross-lane), then a 6-hop xor
// butterfly where each hop merges two sorted-16 lists (16 umax + bmerge16).
// After the butterfly every lane holds the exact global sorted top-16:
// no extraction rounds, no refresh path, no divergence.
__global__ __launch_bounds__(256) void sel_topk_kernel(const float* __restrict__ scores,
                                                       const float* __restrict__ vh,
                                                       float* __restrict__ oslc, int bh0) {
  const int wave = threadIdx.x >> 6, lane = threadIdx.x & 63;
  const int r = blockIdx.x * 4 + wave;  // 1 row per wave
  const int bh = bh0 + (r >> 11);
  const int l = r & 2047;
  const float* srow = scores + (size_t)r * Lc;
  const int l4 = lane * 4;
  u64 m[32];
#pragma unroll
  for (int ii = 0; ii < 8; ++ii) {
    const float4 v = *(const float4*)(srow + ii * 256 + l4);
    const float vv[4] = {v.x, v.y, v.z, v.w};
#pragma unroll
    for (int j = 0; j < 4; ++j) {
      const int key = ii * 256 + l4 + j;
      const unsigned uo = (unsigned)f2o(vv[j]) ^ 0x80000000u;
      m[4 * ii + j] = ((u64)uo << 11) | (u64)(2047 - key);
    }
  }
  // per-lane sorted-16-of-32 build: sorted-2 runs -> 4 -> 8 -> 16, then cap
  // the two sorted-16 runs to the lane-local top-16.
#pragma unroll
  for (int i = 0; i < 32; i += 2) ce(m[i], m[i + 1]);
  merge_runs<2>(m);
  merge_runs<4>(m);
  merge_runs<8>(m);
  u64 t[16];
#pragma unroll
  for (int i = 0; i < 16; ++i) {
    const u64 b = m[31 - i];
    t[i] = m[i] > b ? m[i] : b;
  }
  bmerge<16>(t);

  // 6-hop butterfly: merge sorted-16 with partner's (reversed) sorted-16,
  // keep top-16. After hop mask=32 every lane has the global top-16.
#pragma unroll
  for (int mask = 1; mask <= 32; mask <<= 1) {
#pragma unroll
    for (int i = 0; i < 16; ++i) {
      const u64 p = shflx64(t[15 - i], mask);
      t[i] = t[i] > p ? t[i] : p;
    }
    bmerge<16>(t);
  }

  // softmax over the 16 (t[0] = global max) + V gather; lanes 0..31 = dims,
  // lanes 32..63 duplicate (same cache lines), lane<32 stores.
  const float mtop = o2f((int)((unsigned)(t[0] >> 11) ^ 0x80000000u));
  const int d = lane & 31;
  const float* vb = vh + (size_t)bh * Lc * HDc + d;
  float z = 0.f, oacc = 0.f;
#pragma unroll
  for (int i = 0; i < 16; ++i) {
    const int key = 2047 - (int)((unsigned)t[i] & 0x7ffu);
    const float s = o2f((int)((unsigned)(t[i] >> 11) ^ 0x80000000u));
    const float w_ = __expf(s - mtop);
    z += w_;
    oacc += w_ * vb[(size_t)key * HDc];
  }
  if (lane < 32) oslc[((size_t)bh * Lc + l) * HDc + d] = oacc / z;
}

// ---------- window attention (±32 band) ----------
// Same two-phase structure as cmp_attn: the 64-row group's band spans exactly
// 128 keys [l0-32, l0+95]. Phase A: lane=row, wave-uniform (clamped) s_load
// keys, per-lane band mask -> -1e30 scores; LDS sc[j][row]. Phase B:
// (row,dgrp) threads, fused exp/z/PV with clamped one-line V loads (masked
// weights are exactly 0).
__global__ __launch_bounds__(512) void win_attn_kernel(const float* __restrict__ qh,
                                                       const float* __restrict__ kh,
                                                       const float* __restrict__ vh,
                                                       float* __restrict__ owin) {
  __shared__ float sc[128][65];
  __shared__ float pm[8][64];
  const int tid = threadIdx.x, lane = tid & 63;
  const int w = __builtin_amdgcn_readfirstlane(tid >> 6);
  const int bh = blockIdx.y;
  const int l0 = blockIdx.x * 64;
  const int lrow = l0 + lane;
  const float* q = qh + ((size_t)bh * Lc + lrow) * HDc;
  float qr[HDc];
#pragma unroll
  for (int d = 0; d < HDc; ++d) qr[d] = q[d] * SCALEc;
  const float* kb = kh + (size_t)bh * Lc * HDc;
  float pmax = -1e30f;
#pragma unroll
  for (int i = 0; i < 16; ++i) {
    const int j = w * 16 + i;            // 0..127 (uniform)
    const int key = l0 - 32 + j;         // absolute key (uniform)
    const int keyc = min(max(key, 0), Lc - 1);  // uniform clamp for the load
    float s = dot32q(qr, kb + (size_t)keyc * HDc);
    const int delta = key - lrow;        // lane-varying
    const bool ok = (key >= 0) && (key < Lc) && (delta >= -32) && (delta <= 32);
    s = ok ? s : -1e30f;
    sc[j][lane] = s;
    pmax = fmaxf(pmax, s);
  }
  pm[w][lane] = pmax;
  __syncthreads();

  const int row = tid >> 3;
  const int dg = (tid & 7) * 4;
  float m = pm[0][row];
#pragma unroll
  for (int i = 1; i < 8; ++i) m = fmaxf(m, pm[i][row]);
  const float* vb = vh + (size_t)bh * Lc * HDc + dg;
  float o0 = 0.f, o1 = 0.f, o2 = 0.f, o3 = 0.f, z = 0.f;
#pragma unroll 4
  for (int j = 0; j < 128; ++j) {
    const float wgt = __expf(sc[j][row] - m);  // 0 for masked entries
    z += wgt;
    const int keyc = min(max(l0 - 32 + j, 0), Lc - 1);
    const float4 v = *(const float4*)(vb + (size_t)keyc * HDc);
    o0 += wgt * v.x; o1 += wgt * v.y; o2 += wgt * v.z; o3 += wgt * v.w;
  }
  const float iz = 1.f / z;
  *(float4*)(owin + ((size_t)bh * Lc + l0 + row) * HDc + dg) =
      make_float4(o0 * iz, o1 * iz, o2 * iz, o3 * iz);
}

// ---------- gated combine into merged (B,L,C) ----------
__global__ __launch_bounds__(256) void combine_kernel(const float* __restrict__ ocmp,
                                                      const float* __restrict__ oslc,
                                                      const float* __restrict__ owin,
                                                      const float* __restrict__ gatep,
                                                      float* __restrict__ xm) {
  const int idx = blockIdx.x * 256 + threadIdx.x;  // 4096 rows * 64 float4-groups
  const int c4 = idx & 63, grow = idx >> 6;
  const int b = grow >> 11, l = grow & 2047;
  const int h = c4 >> 3, d4 = (c4 & 7) * 4;
  const size_t hoff = (((size_t)(b * Hc + h) * Lc + l)) * HDc + d4;
  const float g0 = gatep[(size_t)grow * 3 + 0];
  const float g1 = gatep[(size_t)grow * 3 + 1];
  const float g2 = gatep[(size_t)grow * 3 + 2];
  const float4 a = *(const float4*)(ocmp + hoff);
  const float4 s = *(const float4*)(oslc + hoff);
  const float4 w = *(const float4*)(owin + hoff);
  float4 r;
  r.x = g0 * a.x + g1 * s.x + g2 * w.x;
  r.y = g0 * a.y + g1 * s.y + g2 * w.y;
  r.z = g0 * a.z + g1 * s.z + g2 * w.z;
  r.w = g0 * a.w + g1 * s.w + g2 * w.w;
  *(float4*)(xm + (size_t)grow * Cc + c4 * 4) = r;
}

// ---------- launch ----------
extern "C" void kernel_launch(void* const* d_in, const int* in_sizes, int n_in,
                              void* d_out, int out_size, void* d_ws, size_t ws_size,
                              hipStream_t stream) {
  (void)in_sizes; (void)n_in; (void)out_size;
  const float* query = (const float*)d_in[0];
  const float* key   = (const float*)d_in[1];
  const float* value = (const float*)d_in[2];
  const float* Wq = (const float*)d_in[3];
  const float* bq = (const float*)d_in[4];
  const float* Wk = (const float*)d_in[5];
  const float* bk = (const float*)d_in[6];
  const float* Wv = (const float*)d_in[7];
  const float* bv = (const float*)d_in[8];
  const float* Wo = (const float*)d_in[9];
  const float* bo = (const float*)d_in[10];
  const float* WKc = (const float*)d_in[11];
  const float* WVc = (const float*)d_in[12];
  const float* Wpe = (const float*)d_in[13];
  const float* Wg = (const float*)d_in[14];
  const float* bg = (const float*)d_in[15];

  size_t off = 0;
  auto alloc = [&](size_t bytes) -> void* {
    void* p = (char*)d_ws + off;
    off += (bytes + 255) & ~(size_t)255;
    return p;
  };
  float* qh    = (float*)alloc((size_t)TROWSc * HDc * 4);
  float* kh    = (float*)alloc((size_t)TROWSc * HDc * 4);
  float* vh    = (float*)alloc((size_t)TROWSc * HDc * 4);
  float* gatep = (float*)alloc((size_t)ROWSc * 3 * 4);
  float* Kcp   = (float*)alloc((size_t)BHc * NBc * HDc * 4);
  float* Vcp   = (float*)alloc((size_t)BHc * NBc * HDc * 4);
  float* ocmp  = (float*)alloc((size_t)TROWSc * HDc * 4);
  float* oslc  = (float*)alloc((size_t)TROWSc * HDc * 4);
  float* owin  = (float*)alloc((size_t)TROWSc * HDc * 4);
  float* xm    = (float*)alloc((size_t)ROWSc * Cc * 4);

  // scores chunk: G heads x 2048 rows x 2048 keys f32 (G*16.8 MB); chunk by
  // heads if workspace is small.
  const size_t perHead = (size_t)Lc * Lc * 4;
  const size_t avail = (ws_size > off) ? (ws_size - off) : 0;
  int G = 16;
  while (G > 1 && perHead * (size_t)G > avail) G >>= 1;
  float* scores = (float*)alloc(perHead * (size_t)G);

  proj_kernel<<<dim3(512), 256, 0, stream>>>(query, Wq, bq, qh, 1);
  proj_kernel<<<dim3(512), 256, 0, stream>>>(key, Wk, bk, kh, 1);
  proj_kernel<<<dim3(512), 256, 0, stream>>>(value, Wv, bv, vh, 1);
  gate_kernel<<<dim3(16), 256, 0, stream>>>(query, Wg, bg, gatep);
  cmpkv_kernel<<<dim3(256), 256, 0, stream>>>(kh, vh, WKc, WVc, Wpe, Kcp, Vcp);
  cmp_attn_kernel<<<dim3(32, 16), 512, 0, stream>>>(qh, Kcp, Vcp, ocmp);
  for (int c = 0; c < BHc; c += G) {
    score_kernel<<<dim3(32, 4, G), 512, 0, stream>>>(qh, kh, scores, c);
    sel_topk_kernel<<<dim3(G * 512), 256, 0, stream>>>(scores, vh, oslc, c);
  }
  win_attn_kernel<<<dim3(32, 16), 512, 0, stream>>>(qh, kh, vh, owin);
  combine_kernel<<<dim3(1024), 256, 0, stream>>>(ocmp, oslc, owin, gatep, xm);
  proj_kernel<<<dim3(512), 256, 0, stream>>>(xm, Wo, bo, (float*)d_out, 0);
}

// Round 2
// 322.222 us; speedup vs baseline: 1.4029x; 1.4029x over previous
//
#include <hip/hip_runtime.h>
#include <math.h>

// NSA attention (round 14: sel_topk rebuilt as threshold-candidate selection.
// Round 13 post-mortem: VGPR 44 with 48xu64 live state = compiler demoted the
// bitonic arrays to SCRATCH (SROA failure on template-pointer arrays); every
// CE became 2 scratch loads + 2 stores -> 129 us. Even register-resident,
// sorted-merge costs ~2700 VALU/wave (= round-12's 68 us, no win). New
// algorithm has ~1 value/lane state, no arrays: (1) per-lane max of its 32
// scores; (2) warp-bitonic-sort the 64 maxima -> M16 = 16th largest lane max;
// provably M16 <= T(16th overall), so {s >= M16} is a top-16 superset with
// E[count] ~ 18; (3) ballot/mbcnt-compact candidates to LDS, one warp-bitonic
// sort of <=64 by (value desc, key asc) = exact jax tie order (float compares
// so -0==+0 like jax); uniform-branch 2nd-batch merge if N>64 (P~1e-15);
// (4) top-16 in lanes 0..15 -> LDS broadcast -> fused softmax + V gather.
// ~800 instr/wave vs ~2700. B=2 L=2048 C=256 H=8 HD=32 BS=16 SK=16 win=+-32.

#define Bc 2
#define Lc 2048
#define Cc 256
#define Hc 8
#define HDc 32
#define BHc 16          // B*H
#define NBc 128         // L/BS
#define ROWSc 4096      // B*L
#define TROWSc 32768    // B*H*L
#define SCALEc 0.17677669529663687f

// ---------- helpers ----------

__device__ __forceinline__ float dot32q(const float* qr, const float* kr) {
  const float4* k4 = (const float4*)kr;
  float p0 = 0.f, p1 = 0.f, p2 = 0.f, p3 = 0.f;
#pragma unroll
  for (int j = 0; j < 8; j += 4) {
    float4 a = k4[j], b = k4[j + 1], c = k4[j + 2], e = k4[j + 3];
    p0 += a.x * qr[4 * j + 0] + a.y * qr[4 * j + 1] + a.z * qr[4 * j + 2] + a.w * qr[4 * j + 3];
    p1 += b.x * qr[4 * j + 4] + b.y * qr[4 * j + 5] + b.z * qr[4 * j + 6] + b.w * qr[4 * j + 7];
    p2 += c.x * qr[4 * j + 8] + c.y * qr[4 * j + 9] + c.z * qr[4 * j + 10] + c.w * qr[4 * j + 11];
    p3 += e.x * qr[4 * j + 12] + e.y * qr[4 * j + 13] + e.z * qr[4 * j + 14] + e.w * qr[4 * j + 15];
  }
  return (p0 + p1) + (p2 + p3);
}

// ---------- projections ----------
// X(4096,256) @ W(256,256) + bias. headlayout=1: store [b*H+h][l][d]; else [row][c].
__global__ __launch_bounds__(256) void proj_kernel(const float* __restrict__ X,
                                                   const float* __restrict__ W,
                                                   const float* __restrict__ bias,
                                                   float* __restrict__ outp, int headlayout) {
  __shared__ float xs[8 * Cc];
  const int tid = threadIdx.x;
  const int row0 = blockIdx.x * 8;
  {
    const float4* xin = (const float4*)(X + (size_t)row0 * Cc);
    float4* xsv = (float4*)xs;
    xsv[tid] = xin[tid];
    xsv[tid + 256] = xin[tid + 256];
  }
  __syncthreads();
  const int c0 = (tid & 63) * 4;  // 4 consecutive cols
  const int rh = tid >> 6;        // wave id; 2 rows per wave
  float acc[2][4];
#pragma unroll
  for (int r = 0; r < 2; ++r)
#pragma unroll
    for (int c = 0; c < 4; ++c) acc[r][c] = 0.f;

#pragma unroll 4
  for (int d4 = 0; d4 < 64; ++d4) {
    const int d = d4 * 4;
    const float4 w0 = *(const float4*)(W + (size_t)(d + 0) * Cc + c0);
    const float4 w1 = *(const float4*)(W + (size_t)(d + 1) * Cc + c0);
    const float4 w2 = *(const float4*)(W + (size_t)(d + 2) * Cc + c0);
    const float4 w3 = *(const float4*)(W + (size_t)(d + 3) * Cc + c0);
#pragma unroll
    for (int r = 0; r < 2; ++r) {
      const float4 xv = *(const float4*)(xs + (rh * 2 + r) * Cc + d);
      acc[r][0] += xv.x * w0.x + xv.y * w1.x + xv.z * w2.x + xv.w * w3.x;
      acc[r][1] += xv.x * w0.y + xv.y * w1.y + xv.z * w2.y + xv.w * w3.y;
      acc[r][2] += xv.x * w0.z + xv.y * w1.z + xv.z * w2.z + xv.w * w3.z;
      acc[r][3] += xv.x * w0.w + xv.y * w1.w + xv.z * w2.w + xv.w * w3.w;
    }
  }
  const float4 bv = *(const float4*)(bias + c0);
#pragma unroll
  for (int r = 0; r < 2; ++r) {
    const int grow = row0 + rh * 2 + r;
    const float4 o = make_float4(acc[r][0] + bv.x, acc[r][1] + bv.y,
                                 acc[r][2] + bv.z, acc[r][3] + bv.w);
    if (headlayout) {
      const int b = grow >> 11, l = grow & 2047;
      const int h = c0 >> 5, dd = c0 & 31;
      *(float4*)(outp + (((size_t)(b * Hc + h) * Lc + l) * HDc + dd)) = o;
    } else {
      *(float4*)(outp + (size_t)grow * Cc + c0) = o;
    }
  }
}

// gate = sigmoid(query @ Wg + bg), one thread per row
__global__ __launch_bounds__(256) void gate_kernel(const float* __restrict__ query,
                                                   const float* __restrict__ Wg,
                                                   const float* __restrict__ bg,
                                                   float* __restrict__ gatep) {
  const int row = blockIdx.x * 256 + threadIdx.x;
  const float4* x4 = (const float4*)(query + (size_t)row * Cc);
  float a0 = bg[0], a1 = bg[1], a2 = bg[2];
#pragma unroll 8
  for (int d4 = 0; d4 < 64; ++d4) {
    const float4 xv = x4[d4];
    const float* wr = Wg + d4 * 12;
    a0 += xv.x * wr[0] + xv.y * wr[3] + xv.z * wr[6] + xv.w * wr[9];
    a1 += xv.x * wr[1] + xv.y * wr[4] + xv.z * wr[7] + xv.w * wr[10];
    a2 += xv.x * wr[2] + xv.y * wr[5] + xv.z * wr[8] + xv.w * wr[11];
  }
  float* g = gatep + (size_t)row * 3;
  g[0] = 1.f / (1.f + __expf(-a0));
  g[1] = 1.f / (1.f + __expf(-a1));
  g[2] = 1.f / (1.f + __expf(-a2));
}

// ---------- compressed K/V ----------
__global__ __launch_bounds__(256) void cmpkv_kernel(const float* __restrict__ kh,
                                                    const float* __restrict__ vh,
                                                    const float* __restrict__ WKc,
                                                    const float* __restrict__ WVc,
                                                    const float* __restrict__ Wpe,
                                                    float* __restrict__ Kcp,
                                                    float* __restrict__ Vcp) {
  const int idx = blockIdx.x * 256 + threadIdx.x;  // 65536 = bh*128*32
  const int d = idx & 31, n = (idx >> 5) & 127, bh = idx >> 12;
  float pk = 0.f, pv = 0.f;
#pragma unroll
  for (int s = 0; s < 16; ++s) {
    const float pe = Wpe[s * Cc + d];
    pk += pe * WKc[s];
    pv += pe * WVc[s];
  }
  const float* kp = kh + ((size_t)bh * Lc + n * 16) * HDc + d;
  const float* vp = vh + ((size_t)bh * Lc + n * 16) * HDc + d;
  float ak = pk, av = pv;
#pragma unroll
  for (int s = 0; s < 16; ++s) {
    ak += kp[s * HDc] * WKc[s];
    av += vp[s * HDc] * WVc[s];
  }
  Kcp[idx] = ak;
  Vcp[idx] = av;
}

// ---------- compressed attention ----------
__global__ __launch_bounds__(512) void cmp_attn_kernel(const float* __restrict__ qh,
                                                       const float* __restrict__ Kcp,
                                                       const float* __restrict__ Vcp,
                                                       float* __restrict__ ocmp) {
  __shared__ float sc[128][65];
  __shared__ float pm[8][64];
  const int tid = threadIdx.x, lane = tid & 63;
  const int w = __builtin_amdgcn_readfirstlane(tid >> 6);
  const int bh = blockIdx.y;
  const int lrow = blockIdx.x * 64 + lane;
  const float* q = qh + ((size_t)bh * Lc + lrow) * HDc;
  float qr[HDc];
#pragma unroll
  for (int d = 0; d < HDc; ++d) qr[d] = q[d] * SCALEc;
  const float* kcb = Kcp + (size_t)bh * NBc * HDc;
  float pmax = -1e30f;
#pragma unroll
  for (int i = 0; i < 16; ++i) {
    const int key = w * 16 + i;  // uniform
    const float s = dot32q(qr, kcb + (size_t)key * HDc);
    sc[key][lane] = s;
    pmax = fmaxf(pmax, s);
  }
  pm[w][lane] = pmax;
  __syncthreads();

  const int row = tid >> 3;        // 0..63
  const int dg = (tid & 7) * 4;    // dim-group base
  float m = pm[0][row];
#pragma unroll
  for (int i = 1; i < 8; ++i) m = fmaxf(m, pm[i][row]);
  const float* vcb = Vcp + (size_t)bh * NBc * HDc + dg;
  float o0 = 0.f, o1 = 0.f, o2 = 0.f, o3 = 0.f, z = 0.f;
#pragma unroll 4
  for (int key = 0; key < 128; ++key) {
    const float wgt = __expf(sc[key][row] - m);
    z += wgt;
    const float4 v = *(const float4*)(vcb + key * HDc);
    o0 += wgt * v.x; o1 += wgt * v.y; o2 += wgt * v.z; o3 += wgt * v.w;
  }
  const float iz = 1.f / z;
  *(float4*)(ocmp + ((size_t)bh * Lc + blockIdx.x * 64 + row) * HDc + dg) =
      make_float4(o0 * iz, o1 * iz, o2 * iz, o3 * iz);
}

// ---------- selection score pass ----------
__global__ __launch_bounds__(512) void score_kernel(const float* __restrict__ qh,
                                                    const float* __restrict__ kh,
                                                    float* __restrict__ scores, int bh0) {
  __shared__ float sc[64][65];  // [key-in-strip][row], pad 65 -> conflict-free both phases
  const int tid = threadIdx.x, lane = tid & 63;
  const int w = __builtin_amdgcn_readfirstlane(tid >> 6);  // wave id as SGPR (uniform)
  const int hloc = blockIdx.z;           // head within chunk
  const int bh = bh0 + hloc;
  const int q0 = blockIdx.y * 512;       // key-quarter base
  const int lrow = blockIdx.x * 64 + lane;  // row within head
  const float* q = qh + ((size_t)bh * Lc + lrow) * HDc;
  float qr[HDc];
#pragma unroll
  for (int d = 0; d < HDc; ++d) qr[d] = q[d] * SCALEc;
  const float* kb = kh + (size_t)bh * Lc * HDc;
  // store-phase thread mapping: 8 consecutive threads cover one row's 64 keys
  const int srow = tid >> 3;        // 0..63 row-in-tile
  const int skg = (tid & 7) * 8;    // key-group base within strip
  float* srowp = scores + ((size_t)hloc * Lc + (size_t)blockIdx.x * 64 + srow) * Lc + q0;

  for (int strip = 0; strip < 8; ++strip) {
    const int k0 = q0 + strip * 64 + w * 8;  // uniform (SGPR) expression
    float s[8];
#pragma unroll
    for (int j = 0; j < 8; ++j) s[j] = dot32q(qr, kb + (size_t)(k0 + j) * HDc);
    __syncthreads();  // previous strip's store-phase reads complete
#pragma unroll
    for (int j = 0; j < 8; ++j) sc[w * 8 + j][lane] = s[j];
    __syncthreads();
    // store: read sc[skg..skg+7][srow], write 32 B contiguous
    float v[8];
#pragma unroll
    for (int j = 0; j < 8; ++j) v[j] = sc[skg + j][srow];
    float4* dst = (float4*)(srowp + strip * 64 + skg);
    dst[0] = make_float4(v[0], v[1], v[2], v[3]);
    dst[1] = make_float4(v[4], v[5], v[6], v[7]);
  }
}

// ---------- selection top-16 + softmax + V (threshold-candidate) ----------
// One wave per row; lane owns keys {i*256 + lane*4 + j : i<8, j<4} (coalesced
// float4 loads, all values in NAMED float4 regs -> no scratch).
// Phase 1: per-lane max (31 v_max), warp-bitonic sort of the 64 lane maxima
//   (21 shfl stages). M16 = value at lane 15. Since >=16 distinct lanes have
//   max >= M16, count(s >= M16) >= 16, i.e. M16 <= T -> superset guarantee.
// Phase 2: ballot+mbcnt compaction of candidates (s >= M16, E[N]~18) into a
//   per-wave LDS array; one warp-bitonic sort of 64 slots by
//   (value desc, key asc) with FLOAT compares (= exact jax top_k tie order,
//   -0==+0). Pad slots are -inf. If N > 64 (wave-uniform, P~1e-15): sort the
//   second batch of slots and bitonic-merge, keeping the global top.
// Phase 3: lanes 0..15 hold sorted top-16 -> LDS broadcast -> all lanes run
//   fused softmax + V gather (lanes = dims), lane<32 stores.
__global__ __launch_bounds__(256) void sel_topk_kernel(const float* __restrict__ scores,
                                                       const float* __restrict__ vh,
                                                       float* __restrict__ oslc, int bh0) {
  __shared__ float ls_val[4][128];
  __shared__ unsigned ls_key[4][128];
  const int wave = threadIdx.x >> 6, lane = threadIdx.x & 63;
  const int r = blockIdx.x * 4 + wave;  // 1 row per wave
  const int bh = bh0 + (r >> 11);
  const int l = r & 2047;
  const float4* srow4 = (const float4*)(scores + (size_t)r * Lc);
  const int l4 = lane * 4;

  // ---- load 32 scores into named regs, per-lane max ----
  const float4 a0 = srow4[0 * 64 + lane], a1 = srow4[1 * 64 + lane];
  const float4 a2 = srow4[2 * 64 + lane], a3 = srow4[3 * 64 + lane];
  const float4 a4 = srow4[4 * 64 + lane], a5 = srow4[5 * 64 + lane];
  const float4 a6 = srow4[6 * 64 + lane], a7 = srow4[7 * 64 + lane];
  float mx;
  {
    const float m0 = fmaxf(fmaxf(a0.x, a0.y), fmaxf(a0.z, a0.w));
    const float m1 = fmaxf(fmaxf(a1.x, a1.y), fmaxf(a1.z, a1.w));
    const float m2 = fmaxf(fmaxf(a2.x, a2.y), fmaxf(a2.z, a2.w));
    const float m3 = fmaxf(fmaxf(a3.x, a3.y), fmaxf(a3.z, a3.w));
    const float m4 = fmaxf(fmaxf(a4.x, a4.y), fmaxf(a4.z, a4.w));
    const float m5 = fmaxf(fmaxf(a5.x, a5.y), fmaxf(a5.z, a5.w));
    const float m6 = fmaxf(fmaxf(a6.x, a6.y), fmaxf(a6.z, a6.w));
    const float m7 = fmaxf(fmaxf(a7.x, a7.y), fmaxf(a7.z, a7.w));
    mx = fmaxf(fmaxf(fmaxf(m0, m1), fmaxf(m2, m3)),
               fmaxf(fmaxf(m4, m5), fmaxf(m6, m7)));
  }

  // ---- warp bitonic sort of lane maxima (descending across lanes) ----
  float v = mx;
#pragma unroll
  for (int kk = 2; kk <= 64; kk <<= 1) {
#pragma unroll
    for (int j = kk >> 1; j >= 1; j >>= 1) {
      const float o = __shfl_xor(v, j);
      const bool keep_min = (((lane & kk) != 0) == ((lane & j) == 0));
      v = keep_min ? fminf(v, o) : fmaxf(v, o);
    }
  }
  const float M16f = __shfl(v, 15);  // 16th largest lane max (lower bound on T)

  // ---- pad LDS, compact candidates (s >= M16f) ----
  ls_val[wave][lane] = -INFINITY;
  ls_val[wave][64 + lane] = -INFINITY;
  ls_key[wave][lane] = 0x7ffffffeu;
  ls_key[wave][64 + lane] = 0x7fffffffu;
  __asm__ volatile("s_waitcnt lgkmcnt(0)" ::: "memory");

  int base = 0;  // wave-uniform running candidate count
#define CAND(s_, key_)                                                         \
  {                                                                            \
    const bool p_ = (s_) >= M16f;                                              \
    const unsigned long long bm_ = __ballot(p_);                               \
    if (p_) {                                                                  \
      const int pos_ =                                                         \
          base + (int)__builtin_amdgcn_mbcnt_hi(                               \
                     (unsigned)(bm_ >> 32),                                    \
                     __builtin_amdgcn_mbcnt_lo((unsigned)bm_, 0u));            \
      if (pos_ < 128) {                                                        \
        ls_val[wave][pos_] = (s_);                                             \
        ls_key[wave][pos_] = (unsigned)(key_);                                 \
      }                                                                        \
    }                                                                          \
    base += (int)__popcll(bm_);                                                \
  }
  CAND(a0.x, 0 * 256 + l4 + 0) CAND(a0.y, 0 * 256 + l4 + 1)
  CAND(a0.z, 0 * 256 + l4 + 2) CAND(a0.w, 0 * 256 + l4 + 3)
  CAND(a1.x, 1 * 256 + l4 + 0) CAND(a1.y, 1 * 256 + l4 + 1)
  CAND(a1.z, 1 * 256 + l4 + 2) CAND(a1.w, 1 * 256 + l4 + 3)
  CAND(a2.x, 2 * 256 + l4 + 0) CAND(a2.y, 2 * 256 + l4 + 1)
  CAND(a2.z, 2 * 256 + l4 + 2) CAND(a2.w, 2 * 256 + l4 + 3)
  CAND(a3.x, 3 * 256 + l4 + 0) CAND(a3.y, 3 * 256 + l4 + 1)
  CAND(a3.z, 3 * 256 + l4 + 2) CAND(a3.w, 3 * 256 + l4 + 3)
  CAND(a4.x, 4 * 256 + l4 + 0) CAND(a4.y, 4 * 256 + l4 + 1)
  CAND(a4.z, 4 * 256 + l4 + 2) CAND(a4.w, 4 * 256 + l4 + 3)
  CAND(a5.x, 5 * 256 + l4 + 0) CAND(a5.y, 5 * 256 + l4 + 1)
  CAND(a5.z, 5 * 256 + l4 + 2) CAND(a5.w, 5 * 256 + l4 + 3)
  CAND(a6.x, 6 * 256 + l4 + 0) CAND(a6.y, 6 * 256 + l4 + 1)
  CAND(a6.z, 6 * 256 + l4 + 2) CAND(a6.w, 6 * 256 + l4 + 3)
  CAND(a7.x, 7 * 256 + l4 + 0) CAND(a7.y, 7 * 256 + l4 + 1)
  CAND(a7.z, 7 * 256 + l4 + 2) CAND(a7.w, 7 * 256 + l4 + 3)
#undef CAND
  __asm__ volatile("s_waitcnt lgkmcnt(0)" ::: "memory");

  // ---- warp bitonic sort of candidates by (value desc, key asc) ----
  float cv = ls_val[wave][lane];
  unsigned ck = ls_key[wave][lane];
#pragma unroll
  for (int kk = 2; kk <= 64; kk <<= 1) {
#pragma unroll
    for (int j = kk >> 1; j >= 1; j >>= 1) {
      const float ov = __shfl_xor(cv, j);
      const unsigned ok = (unsigned)__shfl_xor((int)ck, j);
      const bool keep_min = (((lane & kk) != 0) == ((lane & j) == 0));
      const bool g = (cv > ov) || (cv == ov && ck < ok);  // I rank earlier
      const bool take = (g == keep_min);
      cv = take ? ov : cv;
      ck = take ? ok : ck;
    }
  }

  if (base > 64) {  // wave-uniform rare path: sort + merge second batch
    float v2 = ls_val[wave][64 + lane];
    unsigned k2 = ls_key[wave][64 + lane];
#pragma unroll
    for (int kk = 2; kk <= 64; kk <<= 1) {
#pragma unroll
      for (int j = kk >> 1; j >= 1; j >>= 1) {
        const float ov = __shfl_xor(v2, j);
        const unsigned ok = (unsigned)__shfl_xor((int)k2, j);
        const bool keep_min = (((lane & kk) != 0) == ((lane & j) == 0));
        const bool g = (v2 > ov) || (v2 == ov && k2 < ok);
        const bool take = (g == keep_min);
        v2 = take ? ov : v2;
        k2 = take ? ok : k2;
      }
    }
    const float rv = __shfl(v2, 63 - lane);
    const unsigned rk = (unsigned)__shfl((int)k2, 63 - lane);
    const bool g2 = (rv > cv) || (rv == cv && rk < ck);
    cv = g2 ? rv : cv;
    ck = g2 ? rk : ck;
#pragma unroll
    for (int j = 32; j >= 1; j >>= 1) {
      const float ov = __shfl_xor(cv, j);
      const unsigned ok = (unsigned)__shfl_xor((int)ck, j);
      const bool keep_min = ((lane & j) != 0);  // descending merge
      const bool g = (cv > ov) || (cv == ov && ck < ok);
      const bool take = (g == keep_min);
      cv = take ? ov : cv;
      ck = take ? ok : ck;
    }
  }

  // ---- broadcast top-16, fused softmax + V gather ----
  if (lane < 16) {
    ls_val[wave][lane] = cv;
    ls_key[wave][lane] = ck;
  }
  __asm__ volatile("s_waitcnt lgkmcnt(0)" ::: "memory");

  const float mtop = ls_val[wave][0];
  const int d = lane & 31;
  const float* vb = vh + (size_t)bh * Lc * HDc + d;
  float z = 0.f, oacc = 0.f;
#pragma unroll
  for (int i = 0; i < 16; ++i) {
    const float w_ = __expf(ls_val[wave][i] - mtop);
    z += w_;
    oacc += w_ * vb[(size_t)ls_key[wave][i] * HDc];
  }
  if (lane < 32) oslc[((size_t)bh * Lc + l) * HDc + d] = oacc / z;
}

// ---------- window attention (±32 band) ----------
__global__ __launch_bounds__(512) void win_attn_kernel(const float* __restrict__ qh,
                                                       const float* __restrict__ kh,
                                                       const float* __restrict__ vh,
                                                       float* __restrict__ owin) {
  __shared__ float sc[128][65];
  __shared__ float pm[8][64];
  const int tid = threadIdx.x, lane = tid & 63;
  const int w = __builtin_amdgcn_readfirstlane(tid >> 6);
  const int bh = blockIdx.y;
  const int l0 = blockIdx.x * 64;
  const int lrow = l0 + lane;
  const float* q = qh + ((size_t)bh * Lc + lrow) * HDc;
  float qr[HDc];
#pragma unroll
  for (int d = 0; d < HDc; ++d) qr[d] = q[d] * SCALEc;
  const float* kb = kh + (size_t)bh * Lc * HDc;
  float pmax = -1e30f;
#pragma unroll
  for (int i = 0; i < 16; ++i) {
    const int j = w * 16 + i;            // 0..127 (uniform)
    const int key = l0 - 32 + j;         // absolute key (uniform)
    const int keyc = min(max(key, 0), Lc - 1);  // uniform clamp for the load
    float s = dot32q(qr, kb + (size_t)keyc * HDc);
    const int delta = key - lrow;        // lane-varying
    const bool ok = (key >= 0) && (key < Lc) && (delta >= -32) && (delta <= 32);
    s = ok ? s : -1e30f;
    sc[j][lane] = s;
    pmax = fmaxf(pmax, s);
  }
  pm[w][lane] = pmax;
  __syncthreads();

  const int row = tid >> 3;
  const int dg = (tid & 7) * 4;
  float m = pm[0][row];
#pragma unroll
  for (int i = 1; i < 8; ++i) m = fmaxf(m, pm[i][row]);
  const float* vb = vh + (size_t)bh * Lc * HDc + dg;
  float o0 = 0.f, o1 = 0.f, o2 = 0.f, o3 = 0.f, z = 0.f;
#pragma unroll 4
  for (int j = 0; j < 128; ++j) {
    const float wgt = __expf(sc[j][row] - m);  // 0 for masked entries
    z += wgt;
    const int keyc = min(max(l0 - 32 + j, 0), Lc - 1);
    const float4 v = *(const float4*)(vb + (size_t)keyc * HDc);
    o0 += wgt * v.x; o1 += wgt * v.y; o2 += wgt * v.z; o3 += wgt * v.w;
  }
  const float iz = 1.f / z;
  *(float4*)(owin + ((size_t)bh * Lc + l0 + row) * HDc + dg) =
      make_float4(o0 * iz, o1 * iz, o2 * iz, o3 * iz);
}

// ---------- gated combine into merged (B,L,C) ----------
__global__ __launch_bounds__(256) void combine_kernel(const float* __restrict__ ocmp,
                                                      const float* __restrict__ oslc,
                                                      const float* __restrict__ owin,
                                                      const float* __restrict__ gatep,
                                                      float* __restrict__ xm) {
  const int idx = blockIdx.x * 256 + threadIdx.x;  // 4096 rows * 64 float4-groups
  const int c4 = idx & 63, grow = idx >> 6;
  const int b = grow >> 11, l = grow & 2047;
  const int h = c4 >> 3, d4 = (c4 & 7) * 4;
  const size_t hoff = (((size_t)(b * Hc + h) * Lc + l)) * HDc + d4;
  const float g0 = gatep[(size_t)grow * 3 + 0];
  const float g1 = gatep[(size_t)grow * 3 + 1];
  const float g2 = gatep[(size_t)grow * 3 + 2];
  const float4 a = *(const float4*)(ocmp + hoff);
  const float4 s = *(const float4*)(oslc + hoff);
  const float4 w = *(const float4*)(owin + hoff);
  float4 r;
  r.x = g0 * a.x + g1 * s.x + g2 * w.x;
  r.y = g0 * a.y + g1 * s.y + g2 * w.y;
  r.z = g0 * a.z + g1 * s.z + g2 * w.z;
  r.w = g0 * a.w + g1 * s.w + g2 * w.w;
  *(float4*)(xm + (size_t)grow * Cc + c4 * 4) = r;
}

// ---------- launch ----------
extern "C" void kernel_launch(void* const* d_in, const int* in_sizes, int n_in,
                              void* d_out, int out_size, void* d_ws, size_t ws_size,
                              hipStream_t stream) {
  (void)in_sizes; (void)n_in; (void)out_size;
  const float* query = (const float*)d_in[0];
  const float* key   = (const float*)d_in[1];
  const float* value = (const float*)d_in[2];
  const float* Wq = (const float*)d_in[3];
  const float* bq = (const float*)d_in[4];
  const float* Wk = (const float*)d_in[5];
  const float* bk = (const float*)d_in[6];
  const float* Wv = (const float*)d_in[7];
  const float* bv = (const float*)d_in[8];
  const float* Wo = (const float*)d_in[9];
  const float* bo = (const float*)d_in[10];
  const float* WKc = (const float*)d_in[11];
  const float* WVc = (const float*)d_in[12];
  const float* Wpe = (const float*)d_in[13];
  const float* Wg = (const float*)d_in[14];
  const float* bg = (const float*)d_in[15];

  size_t off = 0;
  auto alloc = [&](size_t bytes) -> void* {
    void* p = (char*)d_ws + off;
    off += (bytes + 255) & ~(size_t)255;
    return p;
  };
  float* qh    = (float*)alloc((size_t)TROWSc * HDc * 4);
  float* kh    = (float*)alloc((size_t)TROWSc * HDc * 4);
  float* vh    = (float*)alloc((size_t)TROWSc * HDc * 4);
  float* gatep = (float*)alloc((size_t)ROWSc * 3 * 4);
  float* Kcp   = (float*)alloc((size_t)BHc * NBc * HDc * 4);
  float* Vcp   = (float*)alloc((size_t)BHc * NBc * HDc * 4);
  float* ocmp  = (float*)alloc((size_t)TROWSc * HDc * 4);
  float* oslc  = (float*)alloc((size_t)TROWSc * HDc * 4);
  float* owin  = (float*)alloc((size_t)TROWSc * HDc * 4);
  float* xm    = (float*)alloc((size_t)ROWSc * Cc * 4);

  // scores chunk: G heads x 2048 rows x 2048 keys f32 (G*16.8 MB); chunk by
  // heads if workspace is small.
  const size_t perHead = (size_t)Lc * Lc * 4;
  const size_t avail = (ws_size > off) ? (ws_size - off) : 0;
  int G = 16;
  while (G > 1 && perHead * (size_t)G > avail) G >>= 1;
  float* scores = (float*)alloc(perHead * (size_t)G);

  proj_kernel<<<dim3(512), 256, 0, stream>>>(query, Wq, bq, qh, 1);
  proj_kernel<<<dim3(512), 256, 0, stream>>>(key, Wk, bk, kh, 1);
  proj_kernel<<<dim3(512), 256, 0, stream>>>(value, Wv, bv, vh, 1);
  gate_kernel<<<dim3(16), 256, 0, stream>>>(query, Wg, bg, gatep);
  cmpkv_kernel<<<dim3(256), 256, 0, stream>>>(kh, vh, WKc, WVc, Wpe, Kcp, Vcp);
  cmp_attn_kernel<<<dim3(32, 16), 512, 0, stream>>>(qh, Kcp, Vcp, ocmp);
  for (int c = 0; c < BHc; c += G) {
    score_kernel<<<dim3(32, 4, G), 512, 0, stream>>>(qh, kh, scores, c);
    sel_topk_kernel<<<dim3(G * 512), 256, 0, stream>>>(scores, vh, oslc, c);
  }
  win_attn_kernel<<<dim3(32, 16), 512, 0, stream>>>(qh, kh, vh, owin);
  combine_kernel<<<dim3(1024), 256, 0, stream>>>(ocmp, oslc, owin, gatep, xm);
  proj_kernel<<<dim3(512), 256, 0, stream>>>(xm, Wo, bo, (float*)d_out, 0);
}